// Round 10
// baseline (133.871 us; speedup 1.0000x reference)
//
#include <hip/hip_runtime.h>
#include <cstdint>
#include <cstddef>

// ---------------- problem constants ----------------
#define NMEM    128          // ensemble size W
#define WTOTAL  348194       // per-member weight row length (floats)

#define OFF_WOBS   0
#define OFF_BOBS   8192
#define OFF_WACT   8448
#define OFF_BACT   10496
#define OFF_WTGT   10752
#define OFF_BTGT   141824
#define OFF_WS0    142080
#define OFF_BS0    207616
#define OFF_WS1    207872
#define OFF_BS1    273408
#define OFF_WS2    273664
#define OFF_BS2    339200
#define OFF_WSTATE 339456
#define OFF_BSTATE 347648
#define OFF_WREW   347680
#define OFF_BREW   347936
#define OFF_WDONE  347937
#define OFF_BDONE  348193

#define OUT_REW  2097152     // 512*128*32
#define OUT_DONE 2162688     // + 512*128

#define RB 256               // rows (batch) per block -> 2 chunks/member
// pitch 264 elems = 132 dwords == 4 mod 32 -> b128 row-reads are ~2-way bank
// aliasing only (free per m136).
#define APITCH 264

typedef __attribute__((ext_vector_type(8))) short short8;
typedef __attribute__((ext_vector_type(4))) float f32x4;

// pack two f32 -> one dword of 2x bf16 (round-half-up): 2 adds + 1 v_perm.
__device__ __forceinline__ uint32_t pkbf2(float lo, float hi) {
  union { float f; uint32_t u; } a, b;
  a.f = lo; b.f = hi;
  return __builtin_amdgcn_perm(b.u + 0x8000u, a.u + 0x8000u, 0x07060302u);
}

__device__ __forceinline__ uint16_t f2b_fast(float f) {
  union { float f; uint32_t u; } x; x.f = f;
  return (uint16_t)((x.u + 0x8000u) >> 16);
}

__device__ __forceinline__ short8 pk8f2(const float2 f[4]) {
  union { uint32_t u[4]; short8 s; } r;
#pragma unroll
  for (int i = 0; i < 4; ++i) r.u[i] = pkbf2(f[i].x, f[i].y);
  return r.s;
}

__device__ __forceinline__ void zero16(f32x4 acc[16]) {
#pragma unroll
  for (int r = 0; r < 16; ++r)
#pragma unroll
    for (int j = 0; j < 4; ++j) acc[r][j] = 0.0f;
}

// One K=256 pass: wave tile 256 rows x 16 cols.  TWO-slot rotating weight
// staging (8 float2 = 16 VGPRs -- fits the 64 arch-VGPR budget left by the
// 64-AGPR accumulator at 1024thr/1blk-CU): slot kt&1 is packed then refilled
// with kt+2's batch; 16 MFMAs per kt cover the refill latency.
// Weight base 8B-aligned (WTOTAL % 4 == 2) -> float2.
__device__ __forceinline__ void accum_pass(f32x4 acc[16],
                                           const uint16_t* __restrict__ Ab,
                                           const float* __restrict__ w0) {
  float2 g[2][4];
#pragma unroll
  for (int d = 0; d < 2; ++d)
#pragma unroll
    for (int i = 0; i < 4; ++i)
      g[d][i] = reinterpret_cast<const float2*>(w0 + d * 32)[i];

#pragma unroll
  for (int kt = 0; kt < 8; ++kt) {
    const int s = kt & 1;
    const short8 b = pk8f2(g[s]);
    if (kt < 6) {
#pragma unroll
      for (int i = 0; i < 4; ++i)
        g[s][i] = reinterpret_cast<const float2*>(w0 + (kt + 2) * 32)[i];
    }
#pragma unroll
    for (int rt = 0; rt < 16; ++rt) {
      const short8 a =
          *reinterpret_cast<const short8*>(Ab + rt * 16 * APITCH + kt * 32);
      acc[rt] = __builtin_amdgcn_mfma_f32_16x16x32_bf16(a, b, acc[rt], 0, 0, 0);
    }
  }
}

// C/D layout (m89): col = lane&15, row = (lane>>4)*4 + j
__device__ __forceinline__ void epi_lrelu(const f32x4 acc[16], float bv,
                                          uint16_t* __restrict__ B, int c,
                                          int lg) {
#pragma unroll
  for (int rt = 0; rt < 16; ++rt) {
#pragma unroll
    for (int j = 0; j < 4; ++j) {
      float v = acc[rt][j] + bv;
      v = (v > 0.0f) ? v : 0.01f * v;
      B[(rt * 16 + lg * 4 + j) * APITCH + c] = f2b_fast(v);
    }
  }
}

__global__ void __launch_bounds__(1024, 4)
pn_kernel(const float* __restrict__ obs, const float* __restrict__ action,
          const float* __restrict__ w, const float* __restrict__ omin,
          const float* __restrict__ omax, float* __restrict__ out)
{
  // SINGLE activation buffer: 256 x 264 bf16 = 135168 B -> 1 block/CU,
  // grid 256 = exactly one block per CU (no dispatch tail).
  __shared__ __align__(16) uint16_t B1[RB * APITCH];

  const int tid  = threadIdx.x;
  const int lane = tid & 63;
  const int wid  = tid >> 6;        // 0..15
  const int lr   = lane & 15;
  const int lg   = lane >> 4;
  const int c    = wid * 16 + lr;   // this lane's output column (0..255)

  // XCD swizzle: a member's 2 chunk-blocks land on the same XCD; per-layer
  // L2 working set = 16 members x 256KB = 4MB.
  const int bid    = blockIdx.x;
  const int xcd    = bid & 7;
  const int j5     = bid >> 3;           // 0..31
  const int member = xcd * 16 + (j5 >> 1);
  const int chunk  = j5 & 1;
  const int n0     = chunk * RB;
  const float* wm  = w + (size_t)member * WTOTAL;

  const uint16_t* Ab = B1 + lr * APITCH + lg * 8;

  // ---- obs layer: o = lrelu(W_obs @ x + b_obs) -> B1   (K=32, per-rt;
  // normalization recomputed per element to avoid 16 live sc/of regs)
  {
    float2 fb[4];
#pragma unroll
    for (int i = 0; i < 4; ++i)
      fb[i] = reinterpret_cast<const float2*>(wm + OFF_WOBS + c * 32 + lg * 8)[i];
    const short8 b = pk8f2(fb);
    const float bb = wm[OFF_BOBS + c];
    const float4 mn0 = *reinterpret_cast<const float4*>(omin + lg * 8);
    const float4 mn1 = *reinterpret_cast<const float4*>(omin + lg * 8 + 4);
    const float4 mx0 = *reinterpret_cast<const float4*>(omax + lg * 8);
    const float4 mx1 = *reinterpret_cast<const float4*>(omax + lg * 8 + 4);
#pragma unroll
    for (int rt = 0; rt < 16; ++rt) {
      const int n = n0 + rt * 16 + lr;
      const float4 x0 = *reinterpret_cast<const float4*>(obs + n * 32 + lg * 8);
      const float4 x1 = *reinterpret_cast<const float4*>(obs + n * 32 + lg * 8 + 4);
      union { uint32_t u[4]; short8 s; } afr;
      afr.u[0] = pkbf2(2.0f * (x0.x - mn0.x) / (mx0.x - mn0.x) - 1.0f,
                       2.0f * (x0.y - mn0.y) / (mx0.y - mn0.y) - 1.0f);
      afr.u[1] = pkbf2(2.0f * (x0.z - mn0.z) / (mx0.z - mn0.z) - 1.0f,
                       2.0f * (x0.w - mn0.w) / (mx0.w - mn0.w) - 1.0f);
      afr.u[2] = pkbf2(2.0f * (x1.x - mn1.x) / (mx1.x - mn1.x) - 1.0f,
                       2.0f * (x1.y - mn1.y) / (mx1.y - mn1.y) - 1.0f);
      afr.u[3] = pkbf2(2.0f * (x1.z - mn1.z) / (mx1.z - mn1.z) - 1.0f,
                       2.0f * (x1.w - mn1.w) / (mx1.w - mn1.w) - 1.0f);
      f32x4 a0 = {0.0f, 0.0f, 0.0f, 0.0f};
      a0 = __builtin_amdgcn_mfma_f32_16x16x32_bf16(afr.s, b, a0, 0, 0, 0);
#pragma unroll
      for (int j = 0; j < 4; ++j) {
        float v = a0[j] + bb;
        v = (v > 0.0f) ? v : 0.01f * v;
        B1[(rt * 16 + lg * 4 + j) * APITCH + c] = f2b_fast(v);
      }
    }
  }
  __syncthreads();                                   // (1) o ready

  f32x4 acc[16];
  zero16(acc);

  // ---- tgt pass 1: k = 0..255 over o
  accum_pass(acc, Ab, wm + OFF_WTGT + c * 512 + lg * 8);
  __syncthreads();                                   // (2) all reads of o done

  // ---- act layer: a = lrelu(W_act @ action + b_act) -> B1 (overwrite o).
  // K=32 padded: A-frag is zero for lg>0, so junk B values there multiply 0.
  {
    float2 fb[4];
#pragma unroll
    for (int i = 0; i < 4; ++i)
      fb[i] = reinterpret_cast<const float2*>(wm + OFF_WACT + c * 8 + lg * 8)[i];
    const short8 b = pk8f2(fb);
    const float bb = wm[OFF_BACT + c];
#pragma unroll
    for (int rt = 0; rt < 16; ++rt) {
      const int n = n0 + rt * 16 + lr;
      union { uint32_t u[4]; short8 s; } afr;
      if (lg == 0) {
        const float4 q0 = *reinterpret_cast<const float4*>(action + n * 8);
        const float4 q1 = *reinterpret_cast<const float4*>(action + n * 8 + 4);
        afr.u[0] = pkbf2(q0.x, q0.y);
        afr.u[1] = pkbf2(q0.z, q0.w);
        afr.u[2] = pkbf2(q1.x, q1.y);
        afr.u[3] = pkbf2(q1.z, q1.w);
      } else {
        afr.u[0] = afr.u[1] = afr.u[2] = afr.u[3] = 0u;
      }
      f32x4 a0 = {0.0f, 0.0f, 0.0f, 0.0f};
      a0 = __builtin_amdgcn_mfma_f32_16x16x32_bf16(afr.s, b, a0, 0, 0, 0);
#pragma unroll
      for (int j = 0; j < 4; ++j) {
        float v = a0[j] + bb;
        v = (v > 0.0f) ? v : 0.01f * v;
        B1[(rt * 16 + lg * 4 + j) * APITCH + c] = f2b_fast(v);
      }
    }
  }
  __syncthreads();                                   // (3) a ready

  // ---- tgt pass 2: k = 256..511 over a
  accum_pass(acc, Ab, wm + OFF_WTGT + c * 512 + 256 + lg * 8);
  __syncthreads();                                   // (4) reads of a done
  epi_lrelu(acc, wm[OFF_BTGT + c], B1, c, lg);
  __syncthreads();                                   // (5) y0 ready

  // ---- hidden 0 (in-place B1)
  zero16(acc);
  accum_pass(acc, Ab, wm + OFF_WS0 + c * 256 + lg * 8);
  __syncthreads();                                   // (6) reads done
  epi_lrelu(acc, wm[OFF_BS0 + c], B1, c, lg);
  __syncthreads();                                   // (7) y1 ready

  // ---- hidden 1
  zero16(acc);
  accum_pass(acc, Ab, wm + OFF_WS1 + c * 256 + lg * 8);
  __syncthreads();                                   // (8)
  epi_lrelu(acc, wm[OFF_BS1 + c], B1, c, lg);
  __syncthreads();                                   // (9)

  // ---- hidden 2
  zero16(acc);
  accum_pass(acc, Ab, wm + OFF_WS2 + c * 256 + lg * 8);
  __syncthreads();                                   // (10)
  epi_lrelu(acc, wm[OFF_BS2 + c], B1, c, lg);
  __syncthreads();                                   // (11) final y ready

  // ---- head: cols 0..31 = w_state, 32 = w_reward, 33 = w_done  (K=256)
  if (wid < 3) {
    zero16(acc);
#pragma unroll
    for (int kt = 0; kt < 8; ++kt) {
      short8 b;
      if (c < 32) {
        const float* p = wm + OFF_WSTATE + c * 256 + kt * 32 + lg * 8;
        float2 f[4];
#pragma unroll
        for (int i = 0; i < 4; ++i) f[i] = reinterpret_cast<const float2*>(p)[i];
        b = pk8f2(f);
      } else if (c == 32) {
        const float* p = wm + OFF_WREW + kt * 32 + lg * 8;
        float2 f[4];
#pragma unroll
        for (int i = 0; i < 4; ++i) f[i] = reinterpret_cast<const float2*>(p)[i];
        b = pk8f2(f);
      } else if (c == 33) {
        const float* p = wm + OFF_WDONE + kt * 32 + lg * 8;  // odd offset: scalar
        union { uint32_t u[4]; short8 s; } r;
#pragma unroll
        for (int i = 0; i < 4; ++i) r.u[i] = pkbf2(p[2 * i], p[2 * i + 1]);
        b = r.s;
      } else {
        union { uint32_t u[4]; short8 s; } z;
        z.u[0] = z.u[1] = z.u[2] = z.u[3] = 0u;
        b = z.s;
      }
#pragma unroll
      for (int rt = 0; rt < 16; ++rt) {
        const short8 a =
            *reinterpret_cast<const short8*>(Ab + rt * 16 * APITCH + kt * 32);
        acc[rt] = __builtin_amdgcn_mfma_f32_16x16x32_bf16(a, b, acc[rt], 0, 0, 0);
      }
    }

    // ---- head epilogue: f32 residual + un-normalize + tanh/sigmoid
    if (c < 34) {
#pragma unroll
      for (int rt = 0; rt < 16; ++rt) {
#pragma unroll
        for (int j = 0; j < 4; ++j) {
          const int n = n0 + rt * 16 + lg * 4 + j;
          float v = acc[rt][j];
          if (c < 32) {
            const float mn = omin[c], mx = omax[c];
            const float rng = mx - mn;
            const float x = 2.0f * (obs[n * 32 + c] - mn) / rng - 1.0f;
            v += wm[OFF_BSTATE + c] + x;
            v = (v + 1.0f) * 0.5f;
            out[((size_t)n * NMEM + member) * 32 + c] = v * rng + mn;
          } else if (c == 32) {
            v += wm[OFF_BREW];
            out[(size_t)OUT_REW + (size_t)n * NMEM + member] = tanhf(v);
          } else {  // c == 33
            v += wm[OFF_BDONE];
            out[(size_t)OUT_DONE + (size_t)n * NMEM + member] =
                1.0f / (1.0f + expf(-v));
          }
        }
      }
    }
  }
}

extern "C" void kernel_launch(void* const* d_in, const int* in_sizes, int n_in,
                              void* d_out, int out_size, void* d_ws, size_t ws_size,
                              hipStream_t stream) {
  (void)in_sizes; (void)n_in; (void)out_size; (void)d_ws; (void)ws_size;
  const float* obs    = (const float*)d_in[0];
  const float* action = (const float*)d_in[1];
  const float* w      = (const float*)d_in[2];
  const float* omin   = (const float*)d_in[3];
  const float* omax   = (const float*)d_in[4];
  float* out = (float*)d_out;

  pn_kernel<<<dim3(256), dim3(1024), 0, stream>>>(obs, action, w, omin, omax, out);
}

// Round 11
// 123.528 us; speedup vs baseline: 1.0837x; 1.0837x over previous
//
#include <hip/hip_runtime.h>
#include <cstdint>
#include <cstddef>

// ---------------- problem constants ----------------
#define NMEM    128          // ensemble size W
#define WTOTAL  348194       // per-member weight row length (floats)

#define OFF_WOBS   0
#define OFF_BOBS   8192
#define OFF_WACT   8448
#define OFF_BACT   10496
#define OFF_WTGT   10752
#define OFF_BTGT   141824
#define OFF_WS0    142080
#define OFF_BS0    207616
#define OFF_WS1    207872
#define OFF_BS1    273408
#define OFF_WS2    273664
#define OFF_BS2    339200
#define OFF_WSTATE 339456
#define OFF_BSTATE 347648
#define OFF_WREW   347680
#define OFF_BREW   347936
#define OFF_WDONE  347937
#define OFF_BDONE  348193

#define OUT_REW  2097152     // 512*128*32
#define OUT_DONE 2162688     // + 512*128

#define RB 256               // rows (batch) per block -> 2 chunks/member
// pitch 264 elems = 132 dwords == 4 mod 32 -> b128 row-reads spread evenly
// over bank quads (8 lanes per quad = optimum for a 1KB/wave read).
#define APITCH 264

typedef __attribute__((ext_vector_type(8))) short short8;
typedef __attribute__((ext_vector_type(4))) float f32x4;

// pack two f32 -> one dword of 2x bf16 (round-half-up): 2 adds + 1 v_perm.
__device__ __forceinline__ uint32_t pkbf2(float lo, float hi) {
  union { float f; uint32_t u; } a, b;
  a.f = lo; b.f = hi;
  return __builtin_amdgcn_perm(b.u + 0x8000u, a.u + 0x8000u, 0x07060302u);
}

__device__ __forceinline__ uint16_t f2b_fast(float f) {
  union { float f; uint32_t u; } x; x.f = f;
  return (uint16_t)((x.u + 0x8000u) >> 16);
}

__device__ __forceinline__ short8 pk8f2(const float2 f[4]) {
  union { uint32_t u[4]; short8 s; } r;
#pragma unroll
  for (int i = 0; i < 4; ++i) r.u[i] = pkbf2(f[i].x, f[i].y);
  return r.s;
}

__device__ __forceinline__ void zero16(f32x4 acc[16]) {
#pragma unroll
  for (int r = 0; r < 16; ++r)
#pragma unroll
    for (int j = 0; j < 4; ++j) acc[r][j] = 0.0f;
}

// One K=256 pass: wave tile 256 rows x 16 cols.  4-slot rotating weight
// staging (16 float2 = 32 VGPRs): slot kt&3 is packed then refilled with
// kt+4's batch, so 4 load-batches stay in flight; 16 MFMAs per kt cover the
// refill latency.  Weight base 8B-aligned (WTOTAL % 4 == 2) -> float2.
__device__ __forceinline__ void accum_pass(f32x4 acc[16],
                                           const uint16_t* __restrict__ Ab,
                                           const float* __restrict__ w0) {
  float2 g[4][4];
#pragma unroll
  for (int d = 0; d < 4; ++d)
#pragma unroll
    for (int i = 0; i < 4; ++i)
      g[d][i] = reinterpret_cast<const float2*>(w0 + d * 32)[i];

#pragma unroll
  for (int kt = 0; kt < 8; ++kt) {
    const int s = kt & 3;
    const short8 b = pk8f2(g[s]);
    if (kt < 4) {
#pragma unroll
      for (int i = 0; i < 4; ++i)
        g[s][i] = reinterpret_cast<const float2*>(w0 + (kt + 4) * 32)[i];
    }
#pragma unroll
    for (int rt = 0; rt < 16; ++rt) {
      const short8 a =
          *reinterpret_cast<const short8*>(Ab + rt * 16 * APITCH + kt * 32);
      acc[rt] = __builtin_amdgcn_mfma_f32_16x16x32_bf16(a, b, acc[rt], 0, 0, 0);
    }
  }
}

// C/D layout (m89): col = lane&15, row = (lane>>4)*4 + j
__device__ __forceinline__ void epi_lrelu(const f32x4 acc[16], float bv,
                                          uint16_t* __restrict__ B, int c,
                                          int lg) {
#pragma unroll
  for (int rt = 0; rt < 16; ++rt) {
#pragma unroll
    for (int j = 0; j < 4; ++j) {
      float v = acc[rt][j] + bv;
      v = (v > 0.0f) ? v : 0.01f * v;
      B[(rt * 16 + lg * 4 + j) * APITCH + c] = f2b_fast(v);
    }
  }
}

__global__ void __launch_bounds__(1024, 4)
pn_kernel(const float* __restrict__ obs, const float* __restrict__ action,
          const float* __restrict__ w, const float* __restrict__ omin,
          const float* __restrict__ omax, float* __restrict__ out)
{
  // SINGLE activation buffer: 256 x 264 bf16 = 135168 B -> 1 block/CU,
  // grid 256 = exactly one block per CU; the whole batch is one round.
  __shared__ __align__(16) uint16_t B1[RB * APITCH];

  const int tid  = threadIdx.x;
  const int lane = tid & 63;
  const int wid  = tid >> 6;        // 0..15
  const int lr   = lane & 15;
  const int lg   = lane >> 4;
  const int c    = wid * 16 + lr;   // this lane's output column (0..255)

  // XCD swizzle: a member's 2 chunk-blocks land on the same XCD.
  const int bid    = blockIdx.x;
  const int xcd    = bid & 7;
  const int j5     = bid >> 3;           // 0..31
  const int member = xcd * 16 + (j5 >> 1);
  const int chunk  = j5 & 1;
  const int n0     = chunk * RB;
  const float* wm  = w + (size_t)member * WTOTAL;

  const uint16_t* Ab = B1 + lr * APITCH + lg * 8;

  // ---- obs layer: o = lrelu(W_obs @ x + b_obs) -> B1   (K=32, per-rt)
  {
    float2 fb[4];
#pragma unroll
    for (int i = 0; i < 4; ++i)
      fb[i] = reinterpret_cast<const float2*>(wm + OFF_WOBS + c * 32 + lg * 8)[i];
    const short8 b = pk8f2(fb);
    const float bb = wm[OFF_BOBS + c];
    const float4 mn0 = *reinterpret_cast<const float4*>(omin + lg * 8);
    const float4 mn1 = *reinterpret_cast<const float4*>(omin + lg * 8 + 4);
    const float4 mx0 = *reinterpret_cast<const float4*>(omax + lg * 8);
    const float4 mx1 = *reinterpret_cast<const float4*>(omax + lg * 8 + 4);
#pragma unroll
    for (int rt = 0; rt < 16; ++rt) {
      const int n = n0 + rt * 16 + lr;
      const float4 x0 = *reinterpret_cast<const float4*>(obs + n * 32 + lg * 8);
      const float4 x1 = *reinterpret_cast<const float4*>(obs + n * 32 + lg * 8 + 4);
      union { uint32_t u[4]; short8 s; } afr;
      afr.u[0] = pkbf2(2.0f * (x0.x - mn0.x) / (mx0.x - mn0.x) - 1.0f,
                       2.0f * (x0.y - mn0.y) / (mx0.y - mn0.y) - 1.0f);
      afr.u[1] = pkbf2(2.0f * (x0.z - mn0.z) / (mx0.z - mn0.z) - 1.0f,
                       2.0f * (x0.w - mn0.w) / (mx0.w - mn0.w) - 1.0f);
      afr.u[2] = pkbf2(2.0f * (x1.x - mn1.x) / (mx1.x - mn1.x) - 1.0f,
                       2.0f * (x1.y - mn1.y) / (mx1.y - mn1.y) - 1.0f);
      afr.u[3] = pkbf2(2.0f * (x1.z - mn1.z) / (mx1.z - mn1.z) - 1.0f,
                       2.0f * (x1.w - mn1.w) / (mx1.w - mn1.w) - 1.0f);
      f32x4 a0 = {0.0f, 0.0f, 0.0f, 0.0f};
      a0 = __builtin_amdgcn_mfma_f32_16x16x32_bf16(afr.s, b, a0, 0, 0, 0);
#pragma unroll
      for (int j = 0; j < 4; ++j) {
        float v = a0[j] + bb;
        v = (v > 0.0f) ? v : 0.01f * v;
        B1[(rt * 16 + lg * 4 + j) * APITCH + c] = f2b_fast(v);
      }
    }
  }
  __syncthreads();                                   // (1) o ready

  f32x4 acc[16];
  zero16(acc);

  // ---- tgt pass 1: k = 0..255 over o
  accum_pass(acc, Ab, wm + OFF_WTGT + c * 512 + lg * 8);
  __syncthreads();                                   // (2) all reads of o done

  // ---- act layer: a = lrelu(W_act @ action + b_act) -> B1 (overwrite o).
  // K=32 padded: A-frag is zero for lg>0, so junk B values there multiply 0.
  {
    float2 fb[4];
#pragma unroll
    for (int i = 0; i < 4; ++i)
      fb[i] = reinterpret_cast<const float2*>(wm + OFF_WACT + c * 8 + lg * 8)[i];
    const short8 b = pk8f2(fb);
    const float bb = wm[OFF_BACT + c];
#pragma unroll
    for (int rt = 0; rt < 16; ++rt) {
      const int n = n0 + rt * 16 + lr;
      union { uint32_t u[4]; short8 s; } afr;
      if (lg == 0) {
        const float4 q0 = *reinterpret_cast<const float4*>(action + n * 8);
        const float4 q1 = *reinterpret_cast<const float4*>(action + n * 8 + 4);
        afr.u[0] = pkbf2(q0.x, q0.y);
        afr.u[1] = pkbf2(q0.z, q0.w);
        afr.u[2] = pkbf2(q1.x, q1.y);
        afr.u[3] = pkbf2(q1.z, q1.w);
      } else {
        afr.u[0] = afr.u[1] = afr.u[2] = afr.u[3] = 0u;
      }
      f32x4 a0 = {0.0f, 0.0f, 0.0f, 0.0f};
      a0 = __builtin_amdgcn_mfma_f32_16x16x32_bf16(afr.s, b, a0, 0, 0, 0);
#pragma unroll
      for (int j = 0; j < 4; ++j) {
        float v = a0[j] + bb;
        v = (v > 0.0f) ? v : 0.01f * v;
        B1[(rt * 16 + lg * 4 + j) * APITCH + c] = f2b_fast(v);
      }
    }
  }
  __syncthreads();                                   // (3) a ready

  // ---- main K=256 layers as ONE rolled loop (regalloc relief):
  //   L=0: tgt pass 2 (k=256..511 over a; col stride 512; acc carries on)
  //   L=1..3: hidden 0..2 (col stride 256; acc zeroed)
  // Per iter: accum -> barrier(reads done) -> epi -> barrier(y ready).
#pragma unroll 1
  for (int L = 0; L < 4; ++L) {
    const int woff = (L == 0) ? (OFF_WTGT + 256)
                   : (L == 1) ? OFF_WS0
                   : (L == 2) ? OFF_WS1 : OFF_WS2;
    const int boff = (L == 0) ? OFF_BTGT
                   : (L == 1) ? OFF_BS0
                   : (L == 2) ? OFF_BS1 : OFF_BS2;
    const int csh  = (L == 0) ? 9 : 8;   // col stride 512 or 256
    if (L) zero16(acc);
    accum_pass(acc, Ab, wm + woff + (c << csh) + lg * 8);
    __syncthreads();                                 // reads of B1 done
    epi_lrelu(acc, wm[boff + c], B1, c, lg);
    __syncthreads();                                 // new y ready
  }

  // ---- head: cols 0..31 = w_state, 32 = w_reward, 33 = w_done  (K=256)
  if (wid < 3) {
    zero16(acc);
#pragma unroll
    for (int kt = 0; kt < 8; ++kt) {
      short8 b;
      if (c < 32) {
        const float* p = wm + OFF_WSTATE + c * 256 + kt * 32 + lg * 8;
        float2 f[4];
#pragma unroll
        for (int i = 0; i < 4; ++i) f[i] = reinterpret_cast<const float2*>(p)[i];
        b = pk8f2(f);
      } else if (c == 32) {
        const float* p = wm + OFF_WREW + kt * 32 + lg * 8;
        float2 f[4];
#pragma unroll
        for (int i = 0; i < 4; ++i) f[i] = reinterpret_cast<const float2*>(p)[i];
        b = pk8f2(f);
      } else if (c == 33) {
        const float* p = wm + OFF_WDONE + kt * 32 + lg * 8;  // odd offset: scalar
        union { uint32_t u[4]; short8 s; } r;
#pragma unroll
        for (int i = 0; i < 4; ++i) r.u[i] = pkbf2(p[2 * i], p[2 * i + 1]);
        b = r.s;
      } else {
        union { uint32_t u[4]; short8 s; } z;
        z.u[0] = z.u[1] = z.u[2] = z.u[3] = 0u;
        b = z.s;
      }
#pragma unroll
      for (int rt = 0; rt < 16; ++rt) {
        const short8 a =
            *reinterpret_cast<const short8*>(Ab + rt * 16 * APITCH + kt * 32);
        acc[rt] = __builtin_amdgcn_mfma_f32_16x16x32_bf16(a, b, acc[rt], 0, 0, 0);
      }
    }

    // ---- head epilogue: f32 residual + un-normalize + tanh/sigmoid
    if (c < 34) {
#pragma unroll
      for (int rt = 0; rt < 16; ++rt) {
#pragma unroll
        for (int j = 0; j < 4; ++j) {
          const int n = n0 + rt * 16 + lg * 4 + j;
          float v = acc[rt][j];
          if (c < 32) {
            const float mn = omin[c], mx = omax[c];
            const float rng = mx - mn;
            const float x = 2.0f * (obs[n * 32 + c] - mn) / rng - 1.0f;
            v += wm[OFF_BSTATE + c] + x;
            v = (v + 1.0f) * 0.5f;
            out[((size_t)n * NMEM + member) * 32 + c] = v * rng + mn;
          } else if (c == 32) {
            v += wm[OFF_BREW];
            out[(size_t)OUT_REW + (size_t)n * NMEM + member] = tanhf(v);
          } else {  // c == 33
            v += wm[OFF_BDONE];
            out[(size_t)OUT_DONE + (size_t)n * NMEM + member] =
                1.0f / (1.0f + expf(-v));
          }
        }
      }
    }
  }
}

extern "C" void kernel_launch(void* const* d_in, const int* in_sizes, int n_in,
                              void* d_out, int out_size, void* d_ws, size_t ws_size,
                              hipStream_t stream) {
  (void)in_sizes; (void)n_in; (void)out_size; (void)d_ws; (void)ws_size;
  const float* obs    = (const float*)d_in[0];
  const float* action = (const float*)d_in[1];
  const float* w      = (const float*)d_in[2];
  const float* omin   = (const float*)d_in[3];
  const float* omax   = (const float*)d_in[4];
  float* out = (float*)d_out;

  pn_kernel<<<dim3(256), dim3(1024), 0, stream>>>(obs, action, w, omin, omax, out);
}